// Round 4
// baseline (194.275 us; speedup 1.0000x reference)
//
#include <hip/hip_runtime.h>
#include <math.h>

// BarrierNet fused forward, MFMA edition v2.
// r3->r4: mt 4->2 (32 rows/wave), nt loop not unrolled (one B-frag set live),
// launch_bounds(256,2) -> no spills, grid 512 -> 2 blocks/CU. QP phase
// redistributed block-wide (threads 0..127 cover the block's 128 rows).

typedef unsigned int u32;
typedef unsigned short u16;
typedef __attribute__((ext_vector_type(8))) short short8;   // 8 bf16 = 4 VGPR (MFMA A/B)
typedef __attribute__((ext_vector_type(4))) float f32x4;    // MFMA C/D
typedef __attribute__((ext_vector_type(4))) u32 u32x4;      // 16B raw load

union Frag { short8 v; u32 u[4]; u32x4 q; };

__device__ __forceinline__ u16 f2bf(float f) {
    union { float f; u32 i; } v; v.f = f;
    u32 b = v.i;
    return (u16)((b + 0x7fffu + ((b >> 16) & 1u)) >> 16);   // RNE
}
__device__ __forceinline__ u32 packbf(float a, float b) {
    return (u32)f2bf(a) | ((u32)f2bf(b) << 16);
}

// ---------- prep: swizzle W2{1,2} (f32 [128][256]) into bf16 B-fragments ----------
// frag index f = head*4096 + nt*512 + ks*64 + lane ; content j=0..7:
//   W2h[n = nt*16 + (lane&15)][k = ks*32 + (lane>>4)*8 + j]
__global__ __launch_bounds__(256)
void prep_kernel(const float* __restrict__ W21, const float* __restrict__ W22,
                 u32* __restrict__ ws)
{
    int idx  = blockIdx.x * 256 + threadIdx.x;      // 0..8191
    int lane = idx & 63;
    int ks   = (idx >> 6) & 7;
    int nt   = (idx >> 9) & 7;
    int head = idx >> 12;
    const float* W = head ? W22 : W21;
    int n  = nt * 16 + (lane & 15);
    int k0 = ks * 32 + (lane >> 4) * 8;
    const float* s = W + n * 256 + k0;
    u32x4 o;
    o.x = packbf(s[0], s[1]);
    o.y = packbf(s[2], s[3]);
    o.z = packbf(s[4], s[5]);
    o.w = packbf(s[6], s[7]);
    ((u32x4*)ws)[idx] = o;
}

// ---------- main ----------
__global__ __launch_bounds__(256, 2)
void barriernet_kernel(const float* __restrict__ x,      // [B,8]
                       const float* __restrict__ meanp,  // [8]
                       const float* __restrict__ stdp,   // [8]
                       const float* __restrict__ W1,     // [256][8]
                       const float* __restrict__ b1,     // [256]
                       const float* __restrict__ b21,    // [128]
                       const float* __restrict__ W31,    // [2][128]
                       const float* __restrict__ b31,    // [2]
                       const float* __restrict__ b22,    // [128]
                       const float* __restrict__ W32,    // [2][128]
                       const float* __restrict__ b32,    // [2]
                       const u32* __restrict__ wsB,      // swizzled bf16 B-frags
                       float* __restrict__ out, int Btot)
{
    const int tid  = threadIdx.x;
    const int wave = tid >> 6;
    const int lane = tid & 63;
    const int q    = lane >> 4;    // quad
    const int m    = lane & 15;
    const int blockRow = blockIdx.x * 128;
    const int waveRow  = blockRow + wave * 32;   // this wave: 32 rows, 2 M-tiles

    __shared__ float lds_p[128][4];

    // ---- layer 1: compute hid directly as MFMA A-fragments (bf16 packed)
    // A[mt][ks]: lane holds A-frag for row = waveRow + mt*16 + m,
    //            k = ks*32 + q*8 + j (j = 0..7)
    Frag A[2][8];
    #pragma unroll
    for (int mt = 0; mt < 2; ++mt) {
        int R = waveRow + mt * 16 + m;
        float xf[8];
        const float* xp = x + (R < Btot ? R : 0) * 8;
        #pragma unroll
        for (int c = 0; c < 8; ++c) xf[c] = xp[c];
        #pragma unroll
        for (int ks = 0; ks < 8; ++ks) {
            int kb = ks * 32 + q * 8;
            float h[8];
            #pragma unroll
            for (int j = 0; j < 8; ++j) {
                const float* w = W1 + (kb + j) * 8;
                float a = b1[kb + j];
                #pragma unroll
                for (int c = 0; c < 8; ++c) a = fmaf(w[c], xf[c], a);
                h[j] = fmaxf(a, 0.f);
            }
            #pragma unroll
            for (int t = 0; t < 4; ++t)
                A[mt][ks].u[t] = packbf(h[2 * t], h[2 * t + 1]);
        }
    }

    // ---- two heads via MFMA
    #pragma unroll 1
    for (int head = 0; head < 2; ++head) {
        const u32x4* Bbase = (const u32x4*)wsB + head * 4096;
        const float* b2 = head ? b22 : b21;
        const float* W3 = head ? W32 : W31;
        const float* b3 = head ? b32 : b31;

        float pr0[2][4], pr1[2][4];
        #pragma unroll
        for (int mt = 0; mt < 2; ++mt)
            #pragma unroll
            for (int rg = 0; rg < 4; ++rg) { pr0[mt][rg] = 0.f; pr1[mt][rg] = 0.f; }

        #pragma unroll 1
        for (int nt = 0; nt < 8; ++nt) {
            Frag Bf[8];
            #pragma unroll
            for (int ks = 0; ks < 8; ++ks)
                Bf[ks].q = Bbase[nt * 512 + ks * 64 + lane];
            int col = nt * 16 + m;
            float b2c = b2[col];
            float w0c = W3[col];
            float w1c = W3[128 + col];
            #pragma unroll
            for (int mt = 0; mt < 2; ++mt) {
                f32x4 acc = {0.f, 0.f, 0.f, 0.f};
                #pragma unroll
                for (int ks = 0; ks < 8; ++ks)
                    acc = __builtin_amdgcn_mfma_f32_16x16x32_bf16(A[mt][ks].v, Bf[ks].v, acc, 0, 0, 0);
                // acc[rg] = D[row = mt*16 + q*4 + rg][col]
                #pragma unroll
                for (int rg = 0; rg < 4; ++rg) {
                    float rv = fmaxf(acc[rg] + b2c, 0.f);
                    pr0[mt][rg] = fmaf(rv, w0c, pr0[mt][rg]);
                    pr1[mt][rg] = fmaf(rv, w1c, pr1[mt][rg]);
                }
            }
        }

        // reduce over the 16 column-lanes
        #pragma unroll
        for (int mt = 0; mt < 2; ++mt) {
            #pragma unroll
            for (int rg = 0; rg < 4; ++rg) {
                float v0 = pr0[mt][rg], v1 = pr1[mt][rg];
                #pragma unroll
                for (int off = 1; off < 16; off <<= 1) {
                    v0 += __shfl_xor(v0, off, 64);
                    v1 += __shfl_xor(v1, off, 64);
                }
                pr0[mt][rg] = v0; pr1[mt][rg] = v1;
            }
        }
        if (m == 0) {
            #pragma unroll
            for (int mt = 0; mt < 2; ++mt) {
                #pragma unroll
                for (int rg = 0; rg < 4; ++rg) {
                    int row = wave * 32 + mt * 16 + q * 4 + rg;   // row within block
                    float a0 = pr0[mt][rg] + b3[0];
                    float a1 = pr1[mt][rg] + b3[1];
                    if (head == 0) {
                        lds_p[row][0] = a0;
                        lds_p[row][1] = a1;
                    } else {
                        lds_p[row][2] = 4.f / (1.f + expf(-a0));
                        lds_p[row][3] = 4.f / (1.f + expf(-a1));
                    }
                }
            }
        }
    }
    __syncthreads();

    // ---- QP: threads 0..127 each take one of the block's 128 rows
    if (tid >= 128) return;
    int R = blockRow + tid;
    float p0 = lds_p[tid][0];
    float p1 = lds_p[tid][1];
    float s0 = lds_p[tid][2];
    float s1 = lds_p[tid][3];

    float xf[8];
    const float* xp = x + (R < Btot ? R : 0) * 8;
    #pragma unroll
    for (int c = 0; c < 8; ++c) xf[c] = fmaf(xp[c], stdp[c], meanp[c]);
    float px = xf[0], py = xf[1], th = xf[2], v = xf[3];
    float ox = xf[4], oy = xf[5], oth = xf[6], ov = xf[7];

    float st = sinf(th),  ct = cosf(th);
    float so = sinf(oth), co = cosf(oth);
    float vs = v * st, vc = v * ct;
    float sps = s0 + s1, ss = s0 * s1;

    const float obx[8] = { 10.f, 7.07106781186547524f, 6.123234e-16f, -7.07106781186547524f,
                          -10.f, -7.07106781186547524f, -1.8369702e-15f, 7.07106781186547524f };
    const float oby[8] = { 0.f, 7.07106781186547524f, 10.f, 7.07106781186547524f,
                           1.2246468e-15f, -7.07106781186547524f, -10.f, -7.07106781186547524f };
    float Gx[9], Gy[9], hc[9], tol[9];
    float Lf2b = 2.f * v * v;
    #pragma unroll
    for (int k = 0; k < 8; ++k) {
        float dx = px - obx[k], dy = py - oby[k];
        float bar  = dx * dx + dy * dy - 0.64f;
        float bdot = 2.f * dx * vc + 2.f * dy * vs;
        Gx[k] = 2.f * dx * vs - 2.f * dy * vc;
        Gy[k] = -(2.f * dx * ct + 2.f * dy * st);
        hc[k] = Lf2b + sps * bdot + ss * bar;
    }
    {
        float dxo = px - ox, dyo = py - oy;
        float bar_o  = dxo * dxo + dyo * dyo - 0.25f;
        float bdot_o = 2.f * dxo * (vc - ov * co) + 2.f * dyo * (vs - ov * so);
        float Lf2b_o = 2.f * (v * v + ov * ov + 2.f * v * ov * cosf(th - oth));
        Gx[8] = 2.f * dxo * vs - 2.f * dyo * vc;
        Gy[8] = -(2.f * dxo * ct + 2.f * dyo * st);
        hc[8] = Lf2b_o + sps * bdot_o + ss * bar_o;
    }
    #pragma unroll
    for (int k = 0; k < 9; ++k) tol[k] = 1e-6f * (1.f + fabsf(hc[k]));

    float bzx = -p0, bzy = -p1;
    float bobj = INFINITY;
    {
        float zx = -p0, zy = -p1;
        bool f = true;
        #pragma unroll
        for (int k = 0; k < 9; ++k) f = f && (zx * Gx[k] + zy * Gy[k] <= hc[k] + tol[k]);
        if (f) bobj = 0.5f * (zx * zx + zy * zy) + zx * p0 + zy * p1;
    }
    #pragma unroll
    for (int i = 0; i < 9; ++i) {
        float gg  = Gx[i] * Gx[i] + Gy[i] * Gy[i];
        float lam = (-(Gx[i] * p0 + Gy[i] * p1) - hc[i]) / (gg + 1e-12f);
        float zx = -p0 - lam * Gx[i];
        float zy = -p1 - lam * Gy[i];
        bool ok = (lam >= -1e-8f);
        #pragma unroll
        for (int k = 0; k < 9; ++k) ok = ok && (zx * Gx[k] + zy * Gy[k] <= hc[k] + tol[k]);
        float obj = 0.5f * (zx * zx + zy * zy) + zx * p0 + zy * p1;
        if (ok && obj < bobj) { bobj = obj; bzx = zx; bzy = zy; }
    }
    #pragma unroll
    for (int i = 0; i < 8; ++i) {
        #pragma unroll
        for (int j = i + 1; j < 9; ++j) {
            float det = Gx[i] * Gy[j] - Gy[i] * Gx[j];
            bool dok = fabsf(det) > 1e-9f;
            float ds = dok ? det : 1.0f;
            float zx = (hc[i] * Gy[j] - hc[j] * Gy[i]) / ds;
            float zy = (Gx[i] * hc[j] - Gx[j] * hc[i]) / ds;
            float rx = -(zx + p0), ry = -(zy + p1);
            float li = (Gy[j] * rx - Gx[j] * ry) / ds;
            float lj = (Gx[i] * ry - Gy[i] * rx) / ds;
            bool ok = dok && (li >= -1e-8f) && (lj >= -1e-8f);
            #pragma unroll
            for (int k = 0; k < 9; ++k) ok = ok && (zx * Gx[k] + zy * Gy[k] <= hc[k] + tol[k]);
            float obj = 0.5f * (zx * zx + zy * zy) + zx * p0 + zy * p1;
            if (ok && obj < bobj) { bobj = obj; bzx = zx; bzy = zy; }
        }
    }

    if (R < Btot) {
        out[2 * R]     = bzx;
        out[2 * R + 1] = bzy;
    }
}

extern "C" void kernel_launch(void* const* d_in, const int* in_sizes, int n_in,
                              void* d_out, int out_size, void* d_ws, size_t ws_size,
                              hipStream_t stream) {
    const float* x    = (const float*)d_in[0];
    const float* mean = (const float*)d_in[1];
    const float* stdv = (const float*)d_in[2];
    const float* W1   = (const float*)d_in[3];
    const float* b1   = (const float*)d_in[4];
    const float* W21  = (const float*)d_in[5];
    const float* b21  = (const float*)d_in[6];
    const float* W31  = (const float*)d_in[7];
    const float* b31  = (const float*)d_in[8];
    const float* W22  = (const float*)d_in[9];
    const float* b22  = (const float*)d_in[10];
    const float* W32  = (const float*)d_in[11];
    const float* b32  = (const float*)d_in[12];
    int B = in_sizes[0] / 8;
    float* out = (float*)d_out;
    u32* ws = (u32*)d_ws;

    hipLaunchKernelGGL(prep_kernel, dim3(32), dim3(256), 0, stream, W21, W22, ws);

    int blocks = (B + 127) / 128;
    hipLaunchKernelGGL(barriernet_kernel, dim3(blocks), dim3(256), 0, stream,
                       x, mean, stdv, W1, b1, b21, W31, b31, b22, W32, b32,
                       ws, out, B);
}

// Round 5
// 152.130 us; speedup vs baseline: 1.2770x; 1.2770x over previous
//
#include <hip/hip_runtime.h>
#include <math.h>

// BarrierNet fused forward, MFMA edition v3.
// r4->r5: __launch_bounds__(256) with NO min-waves (r4's (256,2) forced a
// 128-VGPR cap -> 190MB spill traffic). Demand ~170 regs -> expect ~192-256
// alloc, no spill, 2 waves/EU naturally. float4 W1 loads, float2 out store.

typedef unsigned int u32;
typedef unsigned short u16;
typedef __attribute__((ext_vector_type(8))) short short8;   // 8 bf16 = 4 VGPR (MFMA A/B)
typedef __attribute__((ext_vector_type(4))) float f32x4;    // MFMA C/D
typedef __attribute__((ext_vector_type(2))) float f32x2;
typedef __attribute__((ext_vector_type(4))) u32 u32x4;      // 16B raw load

union Frag { short8 v; u32 u[4]; u32x4 q; };

__device__ __forceinline__ u16 f2bf(float f) {
    union { float f; u32 i; } v; v.f = f;
    u32 b = v.i;
    return (u16)((b + 0x7fffu + ((b >> 16) & 1u)) >> 16);   // RNE
}
__device__ __forceinline__ u32 packbf(float a, float b) {
    return (u32)f2bf(a) | ((u32)f2bf(b) << 16);
}

// ---------- prep: swizzle W2{1,2} (f32 [128][256]) into bf16 B-fragments ----------
// frag index f = head*4096 + nt*512 + ks*64 + lane ; content j=0..7:
//   W2h[n = nt*16 + (lane&15)][k = ks*32 + (lane>>4)*8 + j]
__global__ __launch_bounds__(256)
void prep_kernel(const float* __restrict__ W21, const float* __restrict__ W22,
                 u32* __restrict__ ws)
{
    int idx  = blockIdx.x * 256 + threadIdx.x;      // 0..8191
    int lane = idx & 63;
    int ks   = (idx >> 6) & 7;
    int nt   = (idx >> 9) & 7;
    int head = idx >> 12;
    const float* W = head ? W22 : W21;
    int n  = nt * 16 + (lane & 15);
    int k0 = ks * 32 + (lane >> 4) * 8;
    const float* s = W + n * 256 + k0;
    u32x4 o;
    o.x = packbf(s[0], s[1]);
    o.y = packbf(s[2], s[3]);
    o.z = packbf(s[4], s[5]);
    o.w = packbf(s[6], s[7]);
    ((u32x4*)ws)[idx] = o;
}

// ---------- main ----------
__global__ __launch_bounds__(256)
void barriernet_kernel(const float* __restrict__ x,      // [B,8]
                       const float* __restrict__ meanp,  // [8]
                       const float* __restrict__ stdp,   // [8]
                       const float* __restrict__ W1,     // [256][8]
                       const float* __restrict__ b1,     // [256]
                       const float* __restrict__ b21,    // [128]
                       const float* __restrict__ W31,    // [2][128]
                       const float* __restrict__ b31,    // [2]
                       const float* __restrict__ b22,    // [128]
                       const float* __restrict__ W32,    // [2][128]
                       const float* __restrict__ b32,    // [2]
                       const u32* __restrict__ wsB,      // swizzled bf16 B-frags
                       float* __restrict__ out, int Btot)
{
    const int tid  = threadIdx.x;
    const int wave = tid >> 6;
    const int lane = tid & 63;
    const int q    = lane >> 4;    // quad
    const int m    = lane & 15;
    const int blockRow = blockIdx.x * 128;
    const int waveRow  = blockRow + wave * 32;   // this wave: 32 rows, 2 M-tiles

    __shared__ float lds_p[128][4];

    // ---- layer 1: compute hid directly as MFMA A-fragments (bf16 packed)
    // A[mt][ks]: lane holds A-frag for row = waveRow + mt*16 + m,
    //            k = ks*32 + q*8 + j (j = 0..7)
    Frag A[2][8];
    const f32x4* W1v = (const f32x4*)W1;
    #pragma unroll
    for (int mt = 0; mt < 2; ++mt) {
        int R = waveRow + mt * 16 + m;
        float xf[8];
        const float* xp = x + (R < Btot ? R : 0) * 8;
        #pragma unroll
        for (int c = 0; c < 8; ++c) xf[c] = xp[c];
        #pragma unroll
        for (int ks = 0; ks < 8; ++ks) {
            int kb = ks * 32 + q * 8;
            float h[8];
            #pragma unroll
            for (int j = 0; j < 8; ++j) {
                f32x4 wa = W1v[(kb + j) * 2];
                f32x4 wb = W1v[(kb + j) * 2 + 1];
                float a = b1[kb + j];
                a = fmaf(wa.x, xf[0], a);
                a = fmaf(wa.y, xf[1], a);
                a = fmaf(wa.z, xf[2], a);
                a = fmaf(wa.w, xf[3], a);
                a = fmaf(wb.x, xf[4], a);
                a = fmaf(wb.y, xf[5], a);
                a = fmaf(wb.z, xf[6], a);
                a = fmaf(wb.w, xf[7], a);
                h[j] = fmaxf(a, 0.f);
            }
            #pragma unroll
            for (int t = 0; t < 4; ++t)
                A[mt][ks].u[t] = packbf(h[2 * t], h[2 * t + 1]);
        }
    }

    // ---- two heads via MFMA
    #pragma unroll 1
    for (int head = 0; head < 2; ++head) {
        const u32x4* Bbase = (const u32x4*)wsB + head * 4096;
        const float* b2 = head ? b22 : b21;
        const float* W3 = head ? W32 : W31;
        const float* b3 = head ? b32 : b31;

        float pr0[2][4], pr1[2][4];
        #pragma unroll
        for (int mt = 0; mt < 2; ++mt)
            #pragma unroll
            for (int rg = 0; rg < 4; ++rg) { pr0[mt][rg] = 0.f; pr1[mt][rg] = 0.f; }

        #pragma unroll 1
        for (int nt = 0; nt < 8; ++nt) {
            Frag Bf[8];
            #pragma unroll
            for (int ks = 0; ks < 8; ++ks)
                Bf[ks].q = Bbase[nt * 512 + ks * 64 + lane];
            int col = nt * 16 + m;
            float b2c = b2[col];
            float w0c = W3[col];
            float w1c = W3[128 + col];
            #pragma unroll
            for (int mt = 0; mt < 2; ++mt) {
                f32x4 acc = {0.f, 0.f, 0.f, 0.f};
                #pragma unroll
                for (int ks = 0; ks < 8; ++ks)
                    acc = __builtin_amdgcn_mfma_f32_16x16x32_bf16(A[mt][ks].v, Bf[ks].v, acc, 0, 0, 0);
                // acc[rg] = D[row = mt*16 + q*4 + rg][col]
                #pragma unroll
                for (int rg = 0; rg < 4; ++rg) {
                    float rv = fmaxf(acc[rg] + b2c, 0.f);
                    pr0[mt][rg] = fmaf(rv, w0c, pr0[mt][rg]);
                    pr1[mt][rg] = fmaf(rv, w1c, pr1[mt][rg]);
                }
            }
        }

        // reduce over the 16 column-lanes
        #pragma unroll
        for (int mt = 0; mt < 2; ++mt) {
            #pragma unroll
            for (int rg = 0; rg < 4; ++rg) {
                float v0 = pr0[mt][rg], v1 = pr1[mt][rg];
                #pragma unroll
                for (int off = 1; off < 16; off <<= 1) {
                    v0 += __shfl_xor(v0, off, 64);
                    v1 += __shfl_xor(v1, off, 64);
                }
                pr0[mt][rg] = v0; pr1[mt][rg] = v1;
            }
        }
        if (m == 0) {
            #pragma unroll
            for (int mt = 0; mt < 2; ++mt) {
                #pragma unroll
                for (int rg = 0; rg < 4; ++rg) {
                    int row = wave * 32 + mt * 16 + q * 4 + rg;   // row within block
                    float a0 = pr0[mt][rg] + b3[0];
                    float a1 = pr1[mt][rg] + b3[1];
                    if (head == 0) {
                        lds_p[row][0] = a0;
                        lds_p[row][1] = a1;
                    } else {
                        lds_p[row][2] = 4.f / (1.f + expf(-a0));
                        lds_p[row][3] = 4.f / (1.f + expf(-a1));
                    }
                }
            }
        }
    }
    __syncthreads();

    // ---- QP: threads 0..127 each take one of the block's 128 rows
    if (tid >= 128) return;
    int R = blockRow + tid;
    float p0 = lds_p[tid][0];
    float p1 = lds_p[tid][1];
    float s0 = lds_p[tid][2];
    float s1 = lds_p[tid][3];

    float xf[8];
    const float* xp = x + (R < Btot ? R : 0) * 8;
    #pragma unroll
    for (int c = 0; c < 8; ++c) xf[c] = fmaf(xp[c], stdp[c], meanp[c]);
    float px = xf[0], py = xf[1], th = xf[2], v = xf[3];
    float ox = xf[4], oy = xf[5], oth = xf[6], ov = xf[7];

    float st = sinf(th),  ct = cosf(th);
    float so = sinf(oth), co = cosf(oth);
    float vs = v * st, vc = v * ct;
    float sps = s0 + s1, ss = s0 * s1;

    const float obx[8] = { 10.f, 7.07106781186547524f, 6.123234e-16f, -7.07106781186547524f,
                          -10.f, -7.07106781186547524f, -1.8369702e-15f, 7.07106781186547524f };
    const float oby[8] = { 0.f, 7.07106781186547524f, 10.f, 7.07106781186547524f,
                           1.2246468e-15f, -7.07106781186547524f, -10.f, -7.07106781186547524f };
    float Gx[9], Gy[9], hc[9], tol[9];
    float Lf2b = 2.f * v * v;
    #pragma unroll
    for (int k = 0; k < 8; ++k) {
        float dx = px - obx[k], dy = py - oby[k];
        float bar  = dx * dx + dy * dy - 0.64f;
        float bdot = 2.f * dx * vc + 2.f * dy * vs;
        Gx[k] = 2.f * dx * vs - 2.f * dy * vc;
        Gy[k] = -(2.f * dx * ct + 2.f * dy * st);
        hc[k] = Lf2b + sps * bdot + ss * bar;
    }
    {
        float dxo = px - ox, dyo = py - oy;
        float bar_o  = dxo * dxo + dyo * dyo - 0.25f;
        float bdot_o = 2.f * dxo * (vc - ov * co) + 2.f * dyo * (vs - ov * so);
        float Lf2b_o = 2.f * (v * v + ov * ov + 2.f * v * ov * cosf(th - oth));
        Gx[8] = 2.f * dxo * vs - 2.f * dyo * vc;
        Gy[8] = -(2.f * dxo * ct + 2.f * dyo * st);
        hc[8] = Lf2b_o + sps * bdot_o + ss * bar_o;
    }
    #pragma unroll
    for (int k = 0; k < 9; ++k) tol[k] = 1e-6f * (1.f + fabsf(hc[k]));

    float bzx = -p0, bzy = -p1;
    float bobj = INFINITY;
    {
        float zx = -p0, zy = -p1;
        bool f = true;
        #pragma unroll
        for (int k = 0; k < 9; ++k) f = f && (zx * Gx[k] + zy * Gy[k] <= hc[k] + tol[k]);
        if (f) bobj = 0.5f * (zx * zx + zy * zy) + zx * p0 + zy * p1;
    }
    #pragma unroll
    for (int i = 0; i < 9; ++i) {
        float gg  = Gx[i] * Gx[i] + Gy[i] * Gy[i];
        float lam = (-(Gx[i] * p0 + Gy[i] * p1) - hc[i]) / (gg + 1e-12f);
        float zx = -p0 - lam * Gx[i];
        float zy = -p1 - lam * Gy[i];
        bool ok = (lam >= -1e-8f);
        #pragma unroll
        for (int k = 0; k < 9; ++k) ok = ok && (zx * Gx[k] + zy * Gy[k] <= hc[k] + tol[k]);
        float obj = 0.5f * (zx * zx + zy * zy) + zx * p0 + zy * p1;
        if (ok && obj < bobj) { bobj = obj; bzx = zx; bzy = zy; }
    }
    #pragma unroll
    for (int i = 0; i < 8; ++i) {
        #pragma unroll
        for (int j = i + 1; j < 9; ++j) {
            float det = Gx[i] * Gy[j] - Gy[i] * Gx[j];
            bool dok = fabsf(det) > 1e-9f;
            float ds = dok ? det : 1.0f;
            float zx = (hc[i] * Gy[j] - hc[j] * Gy[i]) / ds;
            float zy = (Gx[i] * hc[j] - Gx[j] * hc[i]) / ds;
            float rx = -(zx + p0), ry = -(zy + p1);
            float li = (Gy[j] * rx - Gx[j] * ry) / ds;
            float lj = (Gx[i] * ry - Gy[i] * rx) / ds;
            bool ok = dok && (li >= -1e-8f) && (lj >= -1e-8f);
            #pragma unroll
            for (int k = 0; k < 9; ++k) ok = ok && (zx * Gx[k] + zy * Gy[k] <= hc[k] + tol[k]);
            float obj = 0.5f * (zx * zx + zy * zy) + zx * p0 + zy * p1;
            if (ok && obj < bobj) { bobj = obj; bzx = zx; bzy = zy; }
        }
    }

    if (R < Btot) {
        f32x2 o2; o2.x = bzx; o2.y = bzy;
        ((f32x2*)out)[R] = o2;
    }
}

extern "C" void kernel_launch(void* const* d_in, const int* in_sizes, int n_in,
                              void* d_out, int out_size, void* d_ws, size_t ws_size,
                              hipStream_t stream) {
    const float* x    = (const float*)d_in[0];
    const float* mean = (const float*)d_in[1];
    const float* stdv = (const float*)d_in[2];
    const float* W1   = (const float*)d_in[3];
    const float* b1   = (const float*)d_in[4];
    const float* W21  = (const float*)d_in[5];
    const float* b21  = (const float*)d_in[6];
    const float* W31  = (const float*)d_in[7];
    const float* b31  = (const float*)d_in[8];
    const float* W22  = (const float*)d_in[9];
    const float* b22  = (const float*)d_in[10];
    const float* W32  = (const float*)d_in[11];
    const float* b32  = (const float*)d_in[12];
    int B = in_sizes[0] / 8;
    float* out = (float*)d_out;
    u32* ws = (u32*)d_ws;

    hipLaunchKernelGGL(prep_kernel, dim3(32), dim3(256), 0, stream, W21, W22, ws);

    int blocks = (B + 127) / 128;
    hipLaunchKernelGGL(barriernet_kernel, dim3(blocks), dim3(256), 0, stream,
                       x, mean, stdv, W1, b1, b21, W31, b31, b22, W32, b32,
                       ws, out, B);
}

// Round 6
// 131.150 us; speedup vs baseline: 1.4813x; 1.1600x over previous
//
#include <hip/hip_runtime.h>
#include <math.h>

// BarrierNet fused forward, MFMA edition v4.
// r5->r6 theory: r5 was I-cache-thrash-bound (~48KB code > 32KB L1I; 18 cyc/inst).
// Fix: roll everything. QP candidate loop rolled with G/h in LDS (f32x2[9][128]),
// candidates split across thread halves. Layer1 fused into the rolled ks-loop of
// the head GEMM (A-frag transient, acc[mt][nt] static via unrolled nt).

typedef unsigned int u32;
typedef unsigned short u16;
typedef __attribute__((ext_vector_type(8))) short short8;   // 8 bf16 (MFMA A/B)
typedef __attribute__((ext_vector_type(4))) float f32x4;
typedef __attribute__((ext_vector_type(2))) float f32x2;
typedef __attribute__((ext_vector_type(4))) u32 u32x4;

union Frag { short8 v; u32 u[4]; u32x4 q; };

__device__ __forceinline__ u16 f2bf(float f) {
    union { float f; u32 i; } v; v.f = f;
    u32 b = v.i;
    return (u16)((b + 0x7fffu + ((b >> 16) & 1u)) >> 16);   // RNE
}
__device__ __forceinline__ u32 packbf(float a, float b) {
    return (u32)f2bf(a) | ((u32)f2bf(b) << 16);
}

__device__ const float OBX[8] = { 10.f, 7.07106781186547524f, 6.123234e-16f, -7.07106781186547524f,
                                 -10.f, -7.07106781186547524f, -1.8369702e-15f, 7.07106781186547524f };
__device__ const float OBY[8] = { 0.f, 7.07106781186547524f, 10.f, 7.07106781186547524f,
                                  1.2246468e-15f, -7.07106781186547524f, -10.f, -7.07106781186547524f };
// triu_indices(9,1) order
__device__ const unsigned char PI_[36] = {0,0,0,0,0,0,0,0, 1,1,1,1,1,1,1, 2,2,2,2,2,2,
                                          3,3,3,3,3, 4,4,4,4, 5,5,5, 6,6, 7};
__device__ const unsigned char PJ_[36] = {1,2,3,4,5,6,7,8, 2,3,4,5,6,7,8, 3,4,5,6,7,8,
                                          4,5,6,7,8, 5,6,7,8, 6,7,8, 7,8, 8};

// ---------- prep: swizzle W2{1,2} (f32 [128][256]) into bf16 B-fragments ----------
// layout: frag f = ((head*8 + ks)*8 + nt)*64 + lane ; j=0..7:
//   W2h[n = nt*16 + (lane&15)][k = ks*32 + (lane>>4)*8 + j]
__global__ __launch_bounds__(256)
void prep_kernel(const float* __restrict__ W21, const float* __restrict__ W22,
                 u32* __restrict__ ws)
{
    int idx  = blockIdx.x * 256 + threadIdx.x;      // 0..8191
    int lane = idx & 63;
    int nt   = (idx >> 6) & 7;
    int ks   = (idx >> 9) & 7;
    int head = idx >> 12;
    const float* W = head ? W22 : W21;
    int n  = nt * 16 + (lane & 15);
    int k0 = ks * 32 + (lane >> 4) * 8;
    const float* s = W + n * 256 + k0;
    u32x4 o;
    o.x = packbf(s[0], s[1]);
    o.y = packbf(s[2], s[3]);
    o.z = packbf(s[4], s[5]);
    o.w = packbf(s[6], s[7]);
    ((u32x4*)ws)[idx] = o;
}

// ---------- main ----------
__global__ __launch_bounds__(256)
void barriernet_kernel(const float* __restrict__ x,      // [B,8]
                       const float* __restrict__ meanp,  // [8]
                       const float* __restrict__ stdp,   // [8]
                       const float* __restrict__ W1,     // [256][8]
                       const float* __restrict__ b1,     // [256]
                       const float* __restrict__ b21,    // [128]
                       const float* __restrict__ W31,    // [2][128]
                       const float* __restrict__ b31,    // [2]
                       const float* __restrict__ b22,    // [128]
                       const float* __restrict__ W32,    // [2][128]
                       const float* __restrict__ b32,    // [2]
                       const u32* __restrict__ wsB,      // swizzled bf16 B-frags
                       float* __restrict__ out, int Btot)
{
    const int tid  = threadIdx.x;
    const int wave = tid >> 6;
    const int lane = tid & 63;
    const int q    = lane >> 4;
    const int m    = lane & 15;
    const int blockRow = blockIdx.x * 128;
    const int waveRow  = blockRow + wave * 32;

    __shared__ f32x2 qG[9][128];    // (Gx,Gy) per constraint per row
    __shared__ f32x2 qht[9][128];   // (h, tol)
    __shared__ float lds_p[128][4]; // p0,p1,s0,s1 per row
    __shared__ f32x4 res[128];      // half-1 candidate results

    // ---- x rows for this wave's two M-tiles
    float xf0[8], xf1[8];
    {
        int R0 = waveRow + m, R1 = waveRow + 16 + m;
        const float* xp0 = x + (R0 < Btot ? R0 : 0) * 8;
        const float* xp1 = x + (R1 < Btot ? R1 : 0) * 8;
        #pragma unroll
        for (int c = 0; c < 8; ++c) { xf0[c] = xp0[c]; xf1[c] = xp1[c]; }
    }

    const f32x4* W1v = (const f32x4*)W1;
    const f32x4* b1v = (const f32x4*)b1;

    // ---- heads: layer1 fused into rolled ks loop; nt unrolled for static acc
    #pragma unroll 1
    for (int head = 0; head < 2; ++head) {
        const u32x4* Bb = (const u32x4*)wsB + head * 4096 + lane;
        const float* b2 = head ? b22 : b21;
        const float* W3 = head ? W32 : W31;
        const float* b3 = head ? b32 : b31;

        f32x4 acc[2][8];
        #pragma unroll
        for (int mt = 0; mt < 2; ++mt)
            #pragma unroll
            for (int nt = 0; nt < 8; ++nt) acc[mt][nt] = (f32x4){0.f, 0.f, 0.f, 0.f};

        #pragma unroll 1
        for (int ks = 0; ks < 8; ++ks) {
            int kb = ks * 32 + q * 8;
            // layer1: 8 hid values for each of the two row-tiles
            f32x4 bA = b1v[kb >> 2];
            f32x4 bB = b1v[(kb >> 2) + 1];
            Frag A0, A1;
            float h0[8], h1[8];
            #pragma unroll
            for (int j = 0; j < 8; ++j) {
                f32x4 wa = W1v[(kb + j) * 2];
                f32x4 wb = W1v[(kb + j) * 2 + 1];
                float bj = (j < 4) ? bA[j] : bB[j - 4];
                float a0 = bj, a1 = bj;
                a0 = fmaf(wa.x, xf0[0], a0); a1 = fmaf(wa.x, xf1[0], a1);
                a0 = fmaf(wa.y, xf0[1], a0); a1 = fmaf(wa.y, xf1[1], a1);
                a0 = fmaf(wa.z, xf0[2], a0); a1 = fmaf(wa.z, xf1[2], a1);
                a0 = fmaf(wa.w, xf0[3], a0); a1 = fmaf(wa.w, xf1[3], a1);
                a0 = fmaf(wb.x, xf0[4], a0); a1 = fmaf(wb.x, xf1[4], a1);
                a0 = fmaf(wb.y, xf0[5], a0); a1 = fmaf(wb.y, xf1[5], a1);
                a0 = fmaf(wb.z, xf0[6], a0); a1 = fmaf(wb.z, xf1[6], a1);
                a0 = fmaf(wb.w, xf0[7], a0); a1 = fmaf(wb.w, xf1[7], a1);
                h0[j] = fmaxf(a0, 0.f);
                h1[j] = fmaxf(a1, 0.f);
            }
            #pragma unroll
            for (int t = 0; t < 4; ++t) {
                A0.u[t] = packbf(h0[2 * t], h0[2 * t + 1]);
                A1.u[t] = packbf(h1[2 * t], h1[2 * t + 1]);
            }
            const u32x4* Bks = Bb + ks * 512;
            #pragma unroll
            for (int nt = 0; nt < 8; ++nt) {
                Frag Bf; Bf.q = Bks[nt * 64];
                acc[0][nt] = __builtin_amdgcn_mfma_f32_16x16x32_bf16(A0.v, Bf.v, acc[0][nt], 0, 0, 0);
                acc[1][nt] = __builtin_amdgcn_mfma_f32_16x16x32_bf16(A1.v, Bf.v, acc[1][nt], 0, 0, 0);
            }
        }

        // epilogue: bias+relu+W3 dot, then 16-lane reduce
        float pr0[2][4], pr1[2][4];
        #pragma unroll
        for (int mt = 0; mt < 2; ++mt)
            #pragma unroll
            for (int rg = 0; rg < 4; ++rg) { pr0[mt][rg] = 0.f; pr1[mt][rg] = 0.f; }
        #pragma unroll
        for (int nt = 0; nt < 8; ++nt) {
            int col = nt * 16 + m;
            float b2c = b2[col];
            float w0c = W3[col];
            float w1c = W3[128 + col];
            #pragma unroll
            for (int mt = 0; mt < 2; ++mt) {
                #pragma unroll
                for (int rg = 0; rg < 4; ++rg) {
                    float rv = fmaxf(acc[mt][nt][rg] + b2c, 0.f);
                    pr0[mt][rg] = fmaf(rv, w0c, pr0[mt][rg]);
                    pr1[mt][rg] = fmaf(rv, w1c, pr1[mt][rg]);
                }
            }
        }
        #pragma unroll
        for (int mt = 0; mt < 2; ++mt) {
            #pragma unroll
            for (int rg = 0; rg < 4; ++rg) {
                float v0 = pr0[mt][rg], v1 = pr1[mt][rg];
                #pragma unroll
                for (int off = 1; off < 16; off <<= 1) {
                    v0 += __shfl_xor(v0, off, 64);
                    v1 += __shfl_xor(v1, off, 64);
                }
                pr0[mt][rg] = v0; pr1[mt][rg] = v1;
            }
        }
        if (m == 0) {
            #pragma unroll
            for (int mt = 0; mt < 2; ++mt) {
                #pragma unroll
                for (int rg = 0; rg < 4; ++rg) {
                    int row = wave * 32 + mt * 16 + q * 4 + rg;
                    float a0 = pr0[mt][rg] + b3[0];
                    float a1 = pr1[mt][rg] + b3[1];
                    if (head == 0) {
                        lds_p[row][0] = a0;
                        lds_p[row][1] = a1;
                    } else {
                        lds_p[row][2] = 4.f / (1.f + expf(-a0));
                        lds_p[row][3] = 4.f / (1.f + expf(-a1));
                    }
                }
            }
        }
    }
    __syncthreads();

    // ---- QP: rows split rq = tid&127; candidate halves by tid>>7
    const int rq   = tid & 127;
    const int half = tid >> 7;
    const int R    = blockRow + rq;
    float p0 = lds_p[rq][0];
    float p1 = lds_p[rq][1];

    if (half == 0) {
        float s0 = lds_p[rq][2];
        float s1 = lds_p[rq][3];
        float xr[8];
        const float* xp = x + (R < Btot ? R : 0) * 8;
        #pragma unroll
        for (int c = 0; c < 8; ++c) xr[c] = fmaf(xp[c], stdp[c], meanp[c]);
        float px = xr[0], py = xr[1], th = xr[2], v = xr[3];
        float ox = xr[4], oy = xr[5], oth = xr[6], ov = xr[7];
        float st = sinf(th),  ct = cosf(th);
        float so = sinf(oth), co = cosf(oth);
        float vs = v * st, vc = v * ct;
        float sps = s0 + s1, ss = s0 * s1;
        float Lf2b = 2.f * v * v;
        #pragma unroll 1
        for (int k = 0; k < 8; ++k) {
            float dx = px - OBX[k], dy = py - OBY[k];
            float bar  = dx * dx + dy * dy - 0.64f;
            float bdot = 2.f * dx * vc + 2.f * dy * vs;
            float gx = 2.f * dx * vs - 2.f * dy * vc;
            float gy = -(2.f * dx * ct + 2.f * dy * st);
            float hk = Lf2b + sps * bdot + ss * bar;
            qG[k][rq]  = (f32x2){gx, gy};
            qht[k][rq] = (f32x2){hk, 1e-6f * (1.f + fabsf(hk))};
        }
        {
            float dxo = px - ox, dyo = py - oy;
            float bar_o  = dxo * dxo + dyo * dyo - 0.25f;
            float bdot_o = 2.f * dxo * (vc - ov * co) + 2.f * dyo * (vs - ov * so);
            float Lf2b_o = 2.f * (v * v + ov * ov + 2.f * v * ov * cosf(th - oth));
            float gx = 2.f * dxo * vs - 2.f * dyo * vc;
            float gy = -(2.f * dxo * ct + 2.f * dyo * st);
            qG[8][rq]  = (f32x2){gx, gy};
            qht[8][rq] = (f32x2){Lf2b_o + sps * bdot_o + ss * bar_o,
                                 1e-6f * (1.f + fabsf(Lf2b_o + sps * bdot_o + ss * bar_o))};
        }
    }
    __syncthreads();

    // candidates: 0 = unconstrained, 1..9 singles, 10..45 pairs (triu order)
    const int c0 = half ? 23 : 0;
    const int c1 = half ? 46 : 23;
    float bobj = INFINITY;
    float bzx = -p0, bzy = -p1;     // argmin of all-inf -> index 0 -> z0
    #pragma unroll 1
    for (int c = c0; c < c1; ++c) {
        float zx, zy;
        bool pre;
        if (c == 0) {
            zx = -p0; zy = -p1; pre = true;
        } else if (c <= 9) {
            int i = c - 1;
            f32x2 g  = qG[i][rq];
            f32x2 ht = qht[i][rq];
            float gg  = g.x * g.x + g.y * g.y;
            float lam = (-(g.x * p0 + g.y * p1) - ht.x) / (gg + 1e-12f);
            zx = -p0 - lam * g.x;
            zy = -p1 - lam * g.y;
            pre = (lam >= -1e-8f);
        } else {
            int pi = PI_[c - 10], pj = PJ_[c - 10];
            f32x2 gi = qG[pi][rq], gj = qG[pj][rq];
            float hi = qht[pi][rq].x, hj = qht[pj][rq].x;
            float det = gi.x * gj.y - gi.y * gj.x;
            bool dok = fabsf(det) > 1e-9f;
            float ds = dok ? det : 1.0f;
            float inv = 1.0f / ds;
            zx = (hi * gj.y - hj * gi.y) * inv;
            zy = (gi.x * hj - gj.x * hi) * inv;
            float rx = -(zx + p0), ry = -(zy + p1);
            float li = (gj.y * rx - gj.x * ry) * inv;
            float lj = (gi.x * ry - gi.y * rx) * inv;
            pre = dok && (li >= -1e-8f) && (lj >= -1e-8f);
        }
        bool ok = pre;
        #pragma unroll 1
        for (int k = 0; k < 9; ++k) {
            f32x2 g  = qG[k][rq];
            f32x2 ht = qht[k][rq];
            ok = ok && (zx * g.x + zy * g.y <= ht.x + ht.y);
        }
        float obj = 0.5f * (zx * zx + zy * zy) + zx * p0 + zy * p1;
        if (ok && obj < bobj) { bobj = obj; bzx = zx; bzy = zy; }
    }

    if (half) {
        res[rq] = (f32x4){bobj, bzx, bzy, 0.f};
    }
    __syncthreads();
    if (!half) {
        f32x4 r = res[rq];
        if (r.x < bobj) { bzx = r.y; bzy = r.z; }   // strict < keeps first-min order
        if (R < Btot) {
            f32x2 o2; o2.x = bzx; o2.y = bzy;
            ((f32x2*)out)[R] = o2;
        }
    }
}

extern "C" void kernel_launch(void* const* d_in, const int* in_sizes, int n_in,
                              void* d_out, int out_size, void* d_ws, size_t ws_size,
                              hipStream_t stream) {
    const float* x    = (const float*)d_in[0];
    const float* mean = (const float*)d_in[1];
    const float* stdv = (const float*)d_in[2];
    const float* W1   = (const float*)d_in[3];
    const float* b1   = (const float*)d_in[4];
    const float* W21  = (const float*)d_in[5];
    const float* b21  = (const float*)d_in[6];
    const float* W31  = (const float*)d_in[7];
    const float* b31  = (const float*)d_in[8];
    const float* W22  = (const float*)d_in[9];
    const float* b22  = (const float*)d_in[10];
    const float* W32  = (const float*)d_in[11];
    const float* b32  = (const float*)d_in[12];
    int B = in_sizes[0] / 8;
    float* out = (float*)d_out;
    u32* ws = (u32*)d_ws;

    hipLaunchKernelGGL(prep_kernel, dim3(32), dim3(256), 0, stream, W21, W22, ws);

    int blocks = (B + 127) / 128;
    hipLaunchKernelGGL(barriernet_kernel, dim3(blocks), dim3(256), 0, stream,
                       x, mean, stdv, W1, b1, b21, W31, b31, b22, W32, b32,
                       ws, out, B);
}